// Round 6
// baseline (428.670 us; speedup 1.0000x reference)
//
#include <hip/hip_runtime.h>
#include <hip/hip_fp16.h>
#include <math.h>

// Problem constants (fixed by the reference setup_inputs)
#define D      64
#define L      4
#define R      5
#define BGRAPH 1024
#define CT     4096          // edges per coarse-binning block

typedef __attribute__((ext_vector_type(8))) short short8;
typedef __attribute__((ext_vector_type(4))) float f32x4;

__device__ __forceinline__ ushort f2bf(float f) {          // RTN-even fp32->bf16
    unsigned u = __float_as_uint(f);
    return (ushort)((u + 0x7FFFu + ((u >> 16) & 1u)) >> 16);
}
__device__ __forceinline__ float bf2f(ushort h) {
    return __uint_as_float(((unsigned)h) << 16);
}

// ================= two-level MSD sort by dst (no global atomics) =================
// coarse bucket = dst>>8 (196 buckets of 256 nodes); per-block LDS binning.

__global__ void coarse_hist(const int* __restrict__ dst, int* __restrict__ bh,
                            int E, int nbl) {
    __shared__ int cnt[256];
    cnt[threadIdx.x] = 0;
    __syncthreads();
    int base = blockIdx.x * CT;
    int end = base + CT < E ? base + CT : E;
    for (int i = base + threadIdx.x; i < end; i += 256)
        atomicAdd(&cnt[dst[i] >> 8], 1);
    __syncthreads();
    bh[threadIdx.x * nbl + blockIdx.x] = cnt[threadIdx.x];   // [bucket][block]
}

__global__ void scan1(const int* __restrict__ hist, int* __restrict__ offs,
                      int* __restrict__ bsums, int n) {
    __shared__ int tmp[256];
    int i = blockIdx.x * 256 + threadIdx.x;
    int v = (i < n) ? hist[i] : 0;
    tmp[threadIdx.x] = v;
    __syncthreads();
    for (int o = 1; o < 256; o <<= 1) {
        int t = 0;
        if (threadIdx.x >= o) t = tmp[threadIdx.x - o];
        __syncthreads();
        if (threadIdx.x >= o) tmp[threadIdx.x] += t;
        __syncthreads();
    }
    if (i < n) offs[i] = tmp[threadIdx.x] - v;   // exclusive
    if (threadIdx.x == 255) bsums[blockIdx.x] = tmp[255];
}

__global__ void scan2(int* __restrict__ bsums, int nb) {
    __shared__ int tmp[1024];
    int v = (threadIdx.x < nb) ? bsums[threadIdx.x] : 0;
    tmp[threadIdx.x] = v;
    __syncthreads();
    for (int o = 1; o < 1024; o <<= 1) {
        int t = 0;
        if (threadIdx.x >= o) t = tmp[threadIdx.x - o];
        __syncthreads();
        if (threadIdx.x >= o) tmp[threadIdx.x] += t;
        __syncthreads();
    }
    if (threadIdx.x < nb) bsums[threadIdx.x] = tmp[threadIdx.x] - v;  // exclusive
}

__global__ void scan3(int* __restrict__ offs, const int* __restrict__ bsums, int n) {
    int i = blockIdx.x * 256 + threadIdx.x;
    if (i < n) offs[i] += bsums[blockIdx.x];
}

__global__ void coarse_scatter(const int* __restrict__ dst, const int* __restrict__ bh,
                               int* __restrict__ ce, int E, int nbl) {
    __shared__ int cur[256];
    cur[threadIdx.x] = bh[threadIdx.x * nbl + blockIdx.x];
    __syncthreads();
    int base = blockIdx.x * CT;
    int end = base + CT < E ? base + CT : E;
    for (int i = base + threadIdx.x; i < end; i += 256) {
        int pos = atomicAdd(&cur[dst[i] >> 8], 1);     // LDS atomic only
        ce[pos] = i;
    }
}

// fine pass: one block per coarse bucket. Produces offs[] for its 256 nodes and
// the final CSR payload meta[pos] = (src | et<<20, bits(1/cnt(dst,et))).
__global__ __launch_bounds__(512)
void fine_sort(const int* __restrict__ ce, const int* __restrict__ dst,
               const int* __restrict__ et, const int* __restrict__ src,
               const int* __restrict__ bh, int* __restrict__ offs,
               int2* __restrict__ meta, int E, int nbl, int N) {
    __shared__ int cnt[256];
    __shared__ int pref[256];
    __shared__ int cur[256];
    __shared__ int cntR[256 * R];
    int b = blockIdx.x, t = threadIdx.x;
    int rbeg = bh[b * nbl];
    int rend = (b == gridDim.x - 1) ? E : bh[(b + 1) * nbl];
    if (t < 256) { cnt[t] = 0; cur[t] = 0; }
    for (int k = t; k < 256 * R; k += 512) cntR[k] = 0;
    __syncthreads();
    // phase 1: counts per node and per (node, rel)
    for (int i = rbeg + t; i < rend; i += 512) {
        int e = ce[i];
        int ln = dst[e] & 255;
        atomicAdd(&cnt[ln], 1);
        atomicAdd(&cntR[ln * R + et[e]], 1);
    }
    __syncthreads();
    // phase 2: scan 256 node counters; write offs; invert counts
    if (t < 256) pref[t] = cnt[t];
    __syncthreads();
    for (int o = 1; o < 256; o <<= 1) {
        int tv = 0;
        if (t >= o && t < 256) tv = pref[t - o];
        __syncthreads();
        if (t >= o && t < 256) pref[t] += tv;
        __syncthreads();
    }
    if (t < 256) {
        int node = b * 256 + t;
        if (node <= N) offs[node] = rbeg + pref[t] - cnt[t];  // b=195,t=80 -> offs[N]=E
    }
    for (int k = t; k < 256 * R; k += 512) {
        int c = cntR[k];
        ((float*)cntR)[k] = 1.0f / (float)(c > 0 ? c : 1);
    }
    __syncthreads();
    // phase 3: rank + emit payload (writes stay within this bucket's region)
    for (int i = rbeg + t; i < rend; i += 512) {
        int e = ce[i];
        int d = dst[e], r = et[e];
        int ln = d & 255;
        int pos = rbeg + (pref[ln] - cnt[ln]) + atomicAdd(&cur[ln], 1);
        float invc = ((float*)cntR)[ln * R + r];
        meta[pos] = make_int2(src[e] | (r << 20), __float_as_int(invc));
    }
}

// ---- M in split-bf16 B-fragment layout: [l][cg][kt][lane][8], k-rows = [B0|B1|root] ----
__global__ void buildMfrag(const float* __restrict__ basis, const float* __restrict__ root,
                           ushort* __restrict__ Mhi, ushort* __restrict__ Mlo) {
    int t = blockIdx.x * 256 + threadIdx.x;
    if (t >= L * 4 * 6 * 64 * 8) return;
    int j = t & 7;
    int lane = (t >> 3) & 63;
    int rem = t >> 9;              // ((l*4+cg)*6+kt)
    int kt = rem % 6;
    int lcg = rem / 6;
    int cg = lcg & 3, l = lcg >> 2;
    int k = kt * 32 + (lane >> 4) * 8 + j;
    int col = cg * 16 + (lane & 15);
    float val;
    if (k < 64)       val = basis[(((size_t)l * 2 + 0) * D + k) * D + col];
    else if (k < 128) val = basis[(((size_t)l * 2 + 1) * D + (k - 64)) * D + col];
    else              val = root[((size_t)l * D + (k - 128)) * D + col];
    ushort hi = f2bf(val);
    Mhi[t] = hi;
    Mlo[t] = f2bf(val - bf2f(hi));
}

// ---- x -> Z h-cols (fp32) + hf (fp16 gather copy) ----
__global__ void copyX(const float* __restrict__ x, float* __restrict__ Z,
                      __half* __restrict__ hf, int NE) {
    int i = blockIdx.x * 256 + threadIdx.x;
    if (i >= NE) return;
    float v = x[i];
    Z[(size_t)(i >> 6) * 192 + 128 + (i & 63)] = v;
    hf[i] = __float2half(v);
}

// ---- gather: z_b[v] = sum_e (comp[l,et,b]/cnt) * h[src_e]
// edge meta via uniform s_loads; comp selection via SALU cselect chains; 2 fmac/edge
__global__ __launch_bounds__(256)
void gather_k(const int* __restrict__ offs, const int2* __restrict__ meta,
              const __half* __restrict__ hf, const float* __restrict__ comp_l,
              float* __restrict__ Z, int N) {
    int wid = threadIdx.x >> 6, lane = threadIdx.x & 63;
    float c00 = comp_l[0], c01 = comp_l[1], c10 = comp_l[2], c11 = comp_l[3];
    float c20 = comp_l[4], c21 = comp_l[5], c30 = comp_l[6], c31 = comp_l[7];
    float c40 = comp_l[8], c41 = comp_l[9];
    int vbase = (blockIdx.x * 4 + wid) * 4;
    for (int j = 0; j < 4; ++j) {
        int v = vbase + j;
        if (v >= N) return;                    // wave-uniform
        int b  = __builtin_amdgcn_readfirstlane(offs[v]);
        int e2 = __builtin_amdgcn_readfirstlane(offs[v + 1]);
        float s0a = 0.f, s0b = 0.f, s1a = 0.f, s1b = 0.f;
        int i = b;
        #pragma unroll 4
        for (; i + 1 < e2; i += 2) {           // pair-unrolled: gathers in flight
            int2 mA = meta[i], mB = meta[i + 1];               // uniform -> s_load
            float hA = __half2float(hf[(size_t)(mA.x & 0xFFFFF) * D + lane]);
            float hB = __half2float(hf[(size_t)(mB.x & 0xFFFFF) * D + lane]);
            int rA = ((unsigned)mA.x) >> 20, rB = ((unsigned)mB.x) >> 20;
            float icA = __int_as_float(mA.y), icB = __int_as_float(mB.y);
            float a0 = (rA == 0 ? c00 : rA == 1 ? c10 : rA == 2 ? c20 : rA == 3 ? c30 : c40) * icA;
            float a1 = (rA == 0 ? c01 : rA == 1 ? c11 : rA == 2 ? c21 : rA == 3 ? c31 : c41) * icA;
            float b0 = (rB == 0 ? c00 : rB == 1 ? c10 : rB == 2 ? c20 : rB == 3 ? c30 : c40) * icB;
            float b1 = (rB == 0 ? c01 : rB == 1 ? c11 : rB == 2 ? c21 : rB == 3 ? c31 : c41) * icB;
            s0a = fmaf(a0, hA, s0a); s1a = fmaf(a1, hA, s1a);
            s0b = fmaf(b0, hB, s0b); s1b = fmaf(b1, hB, s1b);
        }
        if (i < e2) {
            int2 mA = meta[i];
            float hA = __half2float(hf[(size_t)(mA.x & 0xFFFFF) * D + lane]);
            int rA = ((unsigned)mA.x) >> 20;
            float icA = __int_as_float(mA.y);
            float a0 = (rA == 0 ? c00 : rA == 1 ? c10 : rA == 2 ? c20 : rA == 3 ? c30 : c40) * icA;
            float a1 = (rA == 0 ? c01 : rA == 1 ? c11 : rA == 2 ? c21 : rA == 3 ? c31 : c41) * icA;
            s0a = fmaf(a0, hA, s0a); s1a = fmaf(a1, hA, s1a);
        }
        Z[(size_t)v * 192 + lane]      = s0a + s0b;
        Z[(size_t)v * 192 + 64 + lane] = s1a + s1b;
    }
}

// ---- transform: tanh([z0|z1|h] @ M + bias) via split-bf16 MFMA; IN-PLACE on Z ----
// (each wave reads only the 16 rows it later writes -> no cross-thread hazard)
__global__ __launch_bounds__(256)
void transform_k(float* __restrict__ Z, const ushort* __restrict__ Mhi_l,
                 const ushort* __restrict__ Mlo_l, const float* __restrict__ bias_l,
                 __half* __restrict__ hfo, float* __restrict__ g, int l, int N) {
    int wid = threadIdx.x >> 6, lane = threadIdx.x & 63;
    int tile = blockIdx.x * 4 + wid;
    if (tile * 16 >= N) return;
    int m = lane & 15, lg = lane >> 4;

    // A-frags straight from Z: lane holds row (tile*16+m), k = lg*8 .. +7 per k-tile
    const float* arow = Z + (size_t)(tile * 16 + m) * 192 + lg * 8;
    short8 ahi[6], alo[6];
    #pragma unroll
    for (int kt = 0; kt < 6; ++kt) {
        f32x4 x0 = *(const f32x4*)(arow + kt * 32);
        f32x4 x1 = *(const f32x4*)(arow + kt * 32 + 4);
        union { short8 v; ushort u[8]; } H, Lw;
        #pragma unroll
        for (int q = 0; q < 8; ++q) {
            float f = q < 4 ? x0[q] : x1[q - 4];
            ushort hi = f2bf(f);
            H.u[q] = hi;
            Lw.u[q] = f2bf(f - bf2f(hi));
        }
        ahi[kt] = H.v;
        alo[kt] = Lw.v;
    }

    #pragma unroll
    for (int cg = 0; cg < 4; ++cg) {
        int col = cg * 16 + m;
        float bv = bias_l[col];
        f32x4 acc = { bv, bv, bv, bv };
        #pragma unroll
        for (int kt = 0; kt < 6; ++kt) {
            size_t boff = ((size_t)(cg * 6 + kt) * 64 + lane) * 8;
            short8 bhi = *(const short8*)(Mhi_l + boff);
            short8 blo = *(const short8*)(Mlo_l + boff);
            acc = __builtin_amdgcn_mfma_f32_16x16x32_bf16(ahi[kt], bhi, acc, 0, 0, 0);
            acc = __builtin_amdgcn_mfma_f32_16x16x32_bf16(ahi[kt], blo, acc, 0, 0, 0);
            acc = __builtin_amdgcn_mfma_f32_16x16x32_bf16(alo[kt], bhi, acc, 0, 0, 0);
        }
        int rowbase = tile * 16 + lg * 4;      // C/D: col=lane&15, row=(lane>>4)*4+reg
        #pragma unroll
        for (int r = 0; r < 4; ++r) {
            int node = rowbase + r;
            float tv = tanhf(acc[r]);
            Z[(size_t)node * 192 + 128 + col] = tv;
            hfo[node * D + col] = __float2half(tv);
            if (node < BGRAPH)
                g[(size_t)node * (2 * L * D) + l * D + col] = tv;
            else if (node < 2 * BGRAPH)
                g[(size_t)(node - BGRAPH) * (2 * L * D) + L * D + l * D + col] = tv;
        }
    }
}

// ---- final MLP: 4 rows per block; w1 streamed once per block ----
__global__ void mlp4(const float* __restrict__ g, const float* __restrict__ w1,
                     const float* __restrict__ b1, const float* __restrict__ w2,
                     const float* __restrict__ b2, float* __restrict__ out) {
    __shared__ float gl[4][512];
    __shared__ float red[2][4][128];
    int tid = threadIdx.x;
    int rowbase = blockIdx.x * 4;
    for (int i = tid; i < 4 * 512; i += 256)
        gl[i >> 9][i & 511] = g[(size_t)rowbase * 512 + i];
    __syncthreads();
    int t = tid & 127, kh = tid >> 7;
    float s0 = 0.f, s1 = 0.f, s2 = 0.f, s3 = 0.f;
    int k0 = kh * 256;
    #pragma unroll 4
    for (int k = k0; k < k0 + 256; ++k) {
        float wv = w1[k * 128 + t];
        s0 = fmaf(gl[0][k], wv, s0);
        s1 = fmaf(gl[1][k], wv, s1);
        s2 = fmaf(gl[2][k], wv, s2);
        s3 = fmaf(gl[3][k], wv, s3);
    }
    red[kh][0][t] = s0; red[kh][1][t] = s1; red[kh][2][t] = s2; red[kh][3][t] = s3;
    __syncthreads();
    if (kh == 0) {
        #pragma unroll
        for (int r = 0; r < 4; ++r)
            gl[r][t] = fmaxf(red[0][r][t] + red[1][r][t] + b1[t], 0.f) * w2[t];
    }
    __syncthreads();
    int w = tid >> 6, lane = tid & 63;
    float val = gl[w][lane] + gl[w][lane + 64];
    #pragma unroll
    for (int o = 32; o > 0; o >>= 1) val += __shfl_down(val, o);
    if (lane == 0) out[rowbase + w] = val + b2[0];
}

extern "C" void kernel_launch(void* const* d_in, const int* in_sizes, int n_in,
                              void* d_out, int out_size, void* d_ws, size_t ws_size,
                              hipStream_t stream) {
    const float* x     = (const float*)d_in[0];
    const float* basis = (const float*)d_in[1];
    const float* comp  = (const float*)d_in[2];
    const float* root  = (const float*)d_in[3];
    const float* bias  = (const float*)d_in[4];
    const float* w1    = (const float*)d_in[5];
    const float* b1    = (const float*)d_in[6];
    const float* w2    = (const float*)d_in[7];
    const float* b2    = (const float*)d_in[8];
    const int*   src   = (const int*)d_in[9];
    const int*   dst   = (const int*)d_in[10];
    const int*   et    = (const int*)d_in[11];
    float* out = (float*)d_out;

    const int N = in_sizes[0] / D;   // 50000
    const int E = in_sizes[9];       // 1200000

    const int nbl = (E + CT - 1) / CT;        // 293 coarse blocks
    const int nbh = 256 * nbl;                // bucket-major count array
    const int nbuck = (N + 255) / 256;        // 196 coarse buckets

    // workspace carve-out (~62 MB)
    char* p = (char*)d_ws;
    auto alloc = [&](size_t bytes) -> char* {
        char* q = p;
        p += (bytes + 255) & ~(size_t)255;
        return q;
    };
    int*    offsN = (int*)alloc((size_t)(N + 1) * 4);
    int*    bh    = (int*)alloc((size_t)(nbh + 1) * 4);
    int*    bsums = (int*)alloc(1024 * 4);
    int*    ce    = (int*)alloc((size_t)E * 4);
    int2*   meta  = (int2*)alloc((size_t)E * 8);
    float*  Z     = (float*)alloc((size_t)N * 192 * 4);
    __half* hf    = (__half*)alloc((size_t)N * D * 2);
    float*  gbuf  = (float*)alloc((size_t)BGRAPH * 2 * L * D * 4);
    ushort* Mhi   = (ushort*)alloc((size_t)L * 4 * 6 * 64 * 8 * 2);
    ushort* Mlo   = (ushort*)alloc((size_t)L * 4 * 6 * 64 * 8 * 2);

    // ---- sort phase: LDS binning only, no global atomics ----
    coarse_hist<<<nbl, 256, 0, stream>>>(dst, bh, E, nbl);
    int nb = (nbh + 255) / 256;               // == nbl (nbh multiple of 256)
    scan1<<<nb, 256, 0, stream>>>(bh, bh, bsums, nbh);   // in-place exclusive ok (elementwise)
    scan2<<<1, 1024, 0, stream>>>(bsums, nb);
    scan3<<<nb, 256, 0, stream>>>(bh, bsums, nbh);
    coarse_scatter<<<nbl, 256, 0, stream>>>(dst, bh, ce, E, nbl);
    fine_sort<<<nbuck, 512, 0, stream>>>(ce, dst, et, src, bh, offsN, meta, E, nbl, N);

    buildMfrag<<<(L * 4 * 6 * 64 * 8 + 255) / 256, 256, 0, stream>>>(basis, root, Mhi, Mlo);
    copyX<<<(N * D + 255) / 256, 256, 0, stream>>>(x, Z, hf, N * D);

    // ---- layers ----
    int ggrid = (N + 15) / 16;           // 3125
    int tgrid = ((N + 15) / 16 + 3) / 4; // 782
    for (int l = 0; l < L; ++l) {
        gather_k<<<ggrid, 256, 0, stream>>>(offsN, meta, hf, comp + (size_t)l * R * 2, Z, N);
        transform_k<<<tgrid, 256, 0, stream>>>(Z,
                                               Mhi + (size_t)l * 4 * 6 * 64 * 8,
                                               Mlo + (size_t)l * 4 * 6 * 64 * 8,
                                               bias + (size_t)l * D,
                                               hf, gbuf, l, N);
    }
    mlp4<<<BGRAPH / 4, 256, 0, stream>>>(gbuf, w1, b1, w2, b2, out);
}

// Round 7
// 355.926 us; speedup vs baseline: 1.2044x; 1.2044x over previous
//
#include <hip/hip_runtime.h>
#include <hip/hip_fp16.h>
#include <math.h>

// Problem constants (fixed by the reference setup_inputs)
#define D      64
#define L      4
#define R      5
#define BGRAPH 1024
#define CT     4096          // edges per coarse-binning block

typedef __attribute__((ext_vector_type(8))) short short8;
typedef __attribute__((ext_vector_type(4))) float f32x4;

__device__ __forceinline__ ushort f2bf(float f) {          // RTN-even fp32->bf16
    unsigned u = __float_as_uint(f);
    return (ushort)((u + 0x7FFFu + ((u >> 16) & 1u)) >> 16);
}
__device__ __forceinline__ float bf2f(ushort h) {
    return __uint_as_float(((unsigned)h) << 16);
}

// ================= two-level MSD sort by dst (no global atomics) =================
// coarse bucket = dst>>8 (196 buckets of 256 nodes); per-block LDS binning.

__global__ void coarse_hist(const int* __restrict__ dst, int* __restrict__ bh,
                            int E, int nbl) {
    __shared__ int cnt[256];
    cnt[threadIdx.x] = 0;
    __syncthreads();
    int base = blockIdx.x * CT;
    int end = base + CT < E ? base + CT : E;
    for (int i = base + threadIdx.x; i < end; i += 256)
        atomicAdd(&cnt[dst[i] >> 8], 1);
    __syncthreads();
    bh[threadIdx.x * nbl + blockIdx.x] = cnt[threadIdx.x];   // [bucket][block]
}

__global__ void scan1(const int* __restrict__ hist, int* __restrict__ offs,
                      int* __restrict__ bsums, int n) {
    __shared__ int tmp[256];
    int i = blockIdx.x * 256 + threadIdx.x;
    int v = (i < n) ? hist[i] : 0;
    tmp[threadIdx.x] = v;
    __syncthreads();
    for (int o = 1; o < 256; o <<= 1) {
        int t = 0;
        if (threadIdx.x >= o) t = tmp[threadIdx.x - o];
        __syncthreads();
        if (threadIdx.x >= o) tmp[threadIdx.x] += t;
        __syncthreads();
    }
    if (i < n) offs[i] = tmp[threadIdx.x] - v;   // exclusive
    if (threadIdx.x == 255) bsums[blockIdx.x] = tmp[255];
}

__global__ void scan2(int* __restrict__ bsums, int nb) {
    __shared__ int tmp[1024];
    int v = (threadIdx.x < nb) ? bsums[threadIdx.x] : 0;
    tmp[threadIdx.x] = v;
    __syncthreads();
    for (int o = 1; o < 1024; o <<= 1) {
        int t = 0;
        if (threadIdx.x >= o) t = tmp[threadIdx.x - o];
        __syncthreads();
        if (threadIdx.x >= o) tmp[threadIdx.x] += t;
        __syncthreads();
    }
    if (threadIdx.x < nb) bsums[threadIdx.x] = tmp[threadIdx.x] - v;  // exclusive
}

__global__ void scan3(int* __restrict__ offs, const int* __restrict__ bsums, int n) {
    int i = blockIdx.x * 256 + threadIdx.x;
    if (i < n) offs[i] += bsums[blockIdx.x];
}

__global__ void coarse_scatter(const int* __restrict__ dst, const int* __restrict__ bh,
                               int* __restrict__ ce, int E, int nbl) {
    __shared__ int cur[256];
    cur[threadIdx.x] = bh[threadIdx.x * nbl + blockIdx.x];
    __syncthreads();
    int base = blockIdx.x * CT;
    int end = base + CT < E ? base + CT : E;
    for (int i = base + threadIdx.x; i < end; i += 256) {
        int pos = atomicAdd(&cur[dst[i] >> 8], 1);     // LDS atomic only
        ce[pos] = i;
    }
}

// fine pass: one block per coarse bucket. Produces offs[] for its 256 nodes and
// the final CSR payload: ssrc + per-layer premultiplied weights comp[l,r,b]/cnt.
__global__ __launch_bounds__(512)
void fine_sort(const int* __restrict__ ce, const int* __restrict__ dst,
               const int* __restrict__ et, const int* __restrict__ src,
               const int* __restrict__ bh, const float* __restrict__ comp,
               int* __restrict__ offs, int* __restrict__ ssrc,
               float2* __restrict__ wgtL, int E, int nbl, int N) {
    __shared__ int cnt[256];
    __shared__ int pref[256];
    __shared__ int cur[256];
    __shared__ int cntR[256 * R];
    __shared__ float cshared[L * R * 2];
    int b = blockIdx.x, t = threadIdx.x;
    int rbeg = bh[b * nbl];
    int rend = (b == gridDim.x - 1) ? E : bh[(b + 1) * nbl];
    if (t < 256) { cnt[t] = 0; cur[t] = 0; }
    if (t < L * R * 2) cshared[t] = comp[t];
    for (int k = t; k < 256 * R; k += 512) cntR[k] = 0;
    __syncthreads();
    // phase 1: counts per node and per (node, rel)
    for (int i = rbeg + t; i < rend; i += 512) {
        int e = ce[i];
        int ln = dst[e] & 255;
        atomicAdd(&cnt[ln], 1);
        atomicAdd(&cntR[ln * R + et[e]], 1);
    }
    __syncthreads();
    // phase 2: scan 256 node counters; write offs; invert counts
    if (t < 256) pref[t] = cnt[t];
    __syncthreads();
    for (int o = 1; o < 256; o <<= 1) {
        int tv = 0;
        if (t >= o && t < 256) tv = pref[t - o];
        __syncthreads();
        if (t >= o && t < 256) pref[t] += tv;
        __syncthreads();
    }
    if (t < 256) {
        int node = b * 256 + t;
        if (node <= N) offs[node] = rbeg + pref[t] - cnt[t];  // b=195,t=80 -> offs[N]=E
    }
    for (int k = t; k < 256 * R; k += 512) {
        int c = cntR[k];
        ((float*)cntR)[k] = 1.0f / (float)(c > 0 ? c : 1);
    }
    __syncthreads();
    // phase 3: rank + emit payload (writes stay within this bucket's region)
    for (int i = rbeg + t; i < rend; i += 512) {
        int e = ce[i];
        int d = dst[e], r = et[e];
        int ln = d & 255;
        int pos = rbeg + (pref[ln] - cnt[ln]) + atomicAdd(&cur[ln], 1);
        float invc = ((float*)cntR)[ln * R + r];
        ssrc[pos] = src[e];
        #pragma unroll
        for (int l = 0; l < L; ++l) {
            float2 w;
            w.x = cshared[(l * R + r) * 2 + 0] * invc;
            w.y = cshared[(l * R + r) * 2 + 1] * invc;
            wgtL[(size_t)l * E + pos] = w;
        }
    }
}

// ---- M in split-bf16 B-fragment layout: [l][cg][kt][lane][8], k-rows = [B0|B1|root] ----
__global__ void buildMfrag(const float* __restrict__ basis, const float* __restrict__ root,
                           ushort* __restrict__ Mhi, ushort* __restrict__ Mlo) {
    int t = blockIdx.x * 256 + threadIdx.x;
    if (t >= L * 4 * 6 * 64 * 8) return;
    int j = t & 7;
    int lane = (t >> 3) & 63;
    int rem = t >> 9;              // ((l*4+cg)*6+kt)
    int kt = rem % 6;
    int lcg = rem / 6;
    int cg = lcg & 3, l = lcg >> 2;
    int k = kt * 32 + (lane >> 4) * 8 + j;
    int col = cg * 16 + (lane & 15);
    float val;
    if (k < 64)       val = basis[(((size_t)l * 2 + 0) * D + k) * D + col];
    else if (k < 128) val = basis[(((size_t)l * 2 + 1) * D + (k - 64)) * D + col];
    else              val = root[((size_t)l * D + (k - 128)) * D + col];
    ushort hi = f2bf(val);
    Mhi[t] = hi;
    Mlo[t] = f2bf(val - bf2f(hi));
}

// ---- x -> Z h-cols (fp32) + hf (fp16 gather copy) ----
__global__ void copyX(const float* __restrict__ x, float* __restrict__ Z,
                      __half* __restrict__ hf, int NE) {
    int i = blockIdx.x * 256 + threadIdx.x;
    if (i >= NE) return;
    float v = x[i];
    Z[(size_t)(i >> 6) * 192 + 128 + (i & 63)] = v;
    hf[i] = __float2half(v);
}

// ---- gather: one wave per node; lane = (edge-in-pair, dim-pair)
// one half2 dword load fetches 2 full rows per wave; weights premultiplied.
__global__ __launch_bounds__(256)
void gather_k(const int* __restrict__ offs, const int* __restrict__ ssrc,
              const float2* __restrict__ wgt, const __half2* __restrict__ hf2,
              float* __restrict__ Z, int N) {
    int wid = threadIdx.x >> 6, lane = threadIdx.x & 63;
    int v = blockIdx.x * 4 + wid;
    if (v >= N) return;
    int h = lane >> 5, d2 = lane & 31;
    int b = offs[v], e2 = offs[v + 1];
    float s0l = 0.f, s0h = 0.f, s1l = 0.f, s1h = 0.f;
    #pragma unroll 4
    for (int i = b; i < e2; i += 2) {
        int gi = i + h;
        bool live = gi < e2;
        gi = live ? gi : e2 - 1;
        gi = gi < 0 ? 0 : gi;
        int s = ssrc[gi];                       // 2-way broadcast load
        float2 w = wgt[gi];                     // 2-way broadcast load
        w.x = live ? w.x : 0.f;
        w.y = live ? w.y : 0.f;
        __half2 hv = hf2[(size_t)s * 32 + d2];  // 2 edges x 128B per wave-VMEM
        float lo = __low2float(hv), hi = __high2float(hv);
        s0l = fmaf(w.x, lo, s0l); s0h = fmaf(w.x, hi, s0h);
        s1l = fmaf(w.y, lo, s1l); s1h = fmaf(w.y, hi, s1h);
    }
    s0l += __shfl_xor(s0l, 32); s0h += __shfl_xor(s0h, 32);
    s1l += __shfl_xor(s1l, 32); s1h += __shfl_xor(s1h, 32);
    if (h == 0) {
        *(float2*)(Z + (size_t)v * 192 + 2 * d2)      = make_float2(s0l, s0h);
        *(float2*)(Z + (size_t)v * 192 + 64 + 2 * d2) = make_float2(s1l, s1h);
    }
}

// ---- transform: tanh([z0|z1|h] @ M + bias) via split-bf16 MFMA; IN-PLACE on Z ----
// (each wave reads only the 16 rows it later writes -> no cross-thread hazard)
__global__ __launch_bounds__(256)
void transform_k(float* __restrict__ Z, const ushort* __restrict__ Mhi_l,
                 const ushort* __restrict__ Mlo_l, const float* __restrict__ bias_l,
                 __half* __restrict__ hfo, float* __restrict__ g, int l, int N) {
    int wid = threadIdx.x >> 6, lane = threadIdx.x & 63;
    int tile = blockIdx.x * 4 + wid;
    if (tile * 16 >= N) return;
    int m = lane & 15, lg = lane >> 4;

    // A-frags straight from Z: lane holds row (tile*16+m), k = lg*8 .. +7 per k-tile
    const float* arow = Z + (size_t)(tile * 16 + m) * 192 + lg * 8;
    short8 ahi[6], alo[6];
    #pragma unroll
    for (int kt = 0; kt < 6; ++kt) {
        f32x4 x0 = *(const f32x4*)(arow + kt * 32);
        f32x4 x1 = *(const f32x4*)(arow + kt * 32 + 4);
        union { short8 v; ushort u[8]; } H, Lw;
        #pragma unroll
        for (int q = 0; q < 8; ++q) {
            float f = q < 4 ? x0[q] : x1[q - 4];
            ushort hi = f2bf(f);
            H.u[q] = hi;
            Lw.u[q] = f2bf(f - bf2f(hi));
        }
        ahi[kt] = H.v;
        alo[kt] = Lw.v;
    }

    #pragma unroll
    for (int cg = 0; cg < 4; ++cg) {
        int col = cg * 16 + m;
        float bv = bias_l[col];
        f32x4 acc = { bv, bv, bv, bv };
        #pragma unroll
        for (int kt = 0; kt < 6; ++kt) {
            size_t boff = ((size_t)(cg * 6 + kt) * 64 + lane) * 8;
            short8 bhi = *(const short8*)(Mhi_l + boff);
            short8 blo = *(const short8*)(Mlo_l + boff);
            acc = __builtin_amdgcn_mfma_f32_16x16x32_bf16(ahi[kt], bhi, acc, 0, 0, 0);
            acc = __builtin_amdgcn_mfma_f32_16x16x32_bf16(ahi[kt], blo, acc, 0, 0, 0);
            acc = __builtin_amdgcn_mfma_f32_16x16x32_bf16(alo[kt], bhi, acc, 0, 0, 0);
        }
        int rowbase = tile * 16 + lg * 4;      // C/D: col=lane&15, row=(lane>>4)*4+reg
        #pragma unroll
        for (int r = 0; r < 4; ++r) {
            int node = rowbase + r;
            float tv = tanhf(acc[r]);
            Z[(size_t)node * 192 + 128 + col] = tv;
            hfo[node * D + col] = __float2half(tv);
            if (node < BGRAPH)
                g[(size_t)node * (2 * L * D) + l * D + col] = tv;
            else if (node < 2 * BGRAPH)
                g[(size_t)(node - BGRAPH) * (2 * L * D) + L * D + l * D + col] = tv;
        }
    }
}

// ---- final MLP: 4 rows per block; w1 streamed once per block ----
__global__ void mlp4(const float* __restrict__ g, const float* __restrict__ w1,
                     const float* __restrict__ b1, const float* __restrict__ w2,
                     const float* __restrict__ b2, float* __restrict__ out) {
    __shared__ float gl[4][512];
    __shared__ float red[2][4][128];
    int tid = threadIdx.x;
    int rowbase = blockIdx.x * 4;
    for (int i = tid; i < 4 * 512; i += 256)
        gl[i >> 9][i & 511] = g[(size_t)rowbase * 512 + i];
    __syncthreads();
    int t = tid & 127, kh = tid >> 7;
    float s0 = 0.f, s1 = 0.f, s2 = 0.f, s3 = 0.f;
    int k0 = kh * 256;
    #pragma unroll 4
    for (int k = k0; k < k0 + 256; ++k) {
        float wv = w1[k * 128 + t];
        s0 = fmaf(gl[0][k], wv, s0);
        s1 = fmaf(gl[1][k], wv, s1);
        s2 = fmaf(gl[2][k], wv, s2);
        s3 = fmaf(gl[3][k], wv, s3);
    }
    red[kh][0][t] = s0; red[kh][1][t] = s1; red[kh][2][t] = s2; red[kh][3][t] = s3;
    __syncthreads();
    if (kh == 0) {
        #pragma unroll
        for (int r = 0; r < 4; ++r)
            gl[r][t] = fmaxf(red[0][r][t] + red[1][r][t] + b1[t], 0.f) * w2[t];
    }
    __syncthreads();
    int w = tid >> 6, lane = tid & 63;
    float val = gl[w][lane] + gl[w][lane + 64];
    #pragma unroll
    for (int o = 32; o > 0; o >>= 1) val += __shfl_down(val, o);
    if (lane == 0) out[rowbase + w] = val + b2[0];
}

extern "C" void kernel_launch(void* const* d_in, const int* in_sizes, int n_in,
                              void* d_out, int out_size, void* d_ws, size_t ws_size,
                              hipStream_t stream) {
    const float* x     = (const float*)d_in[0];
    const float* basis = (const float*)d_in[1];
    const float* comp  = (const float*)d_in[2];
    const float* root  = (const float*)d_in[3];
    const float* bias  = (const float*)d_in[4];
    const float* w1    = (const float*)d_in[5];
    const float* b1    = (const float*)d_in[6];
    const float* w2    = (const float*)d_in[7];
    const float* b2    = (const float*)d_in[8];
    const int*   src   = (const int*)d_in[9];
    const int*   dst   = (const int*)d_in[10];
    const int*   et    = (const int*)d_in[11];
    float* out = (float*)d_out;

    const int N = in_sizes[0] / D;   // 50000
    const int E = in_sizes[9];       // 1200000

    const int nbl = (E + CT - 1) / CT;        // 293 coarse blocks
    const int nbh = 256 * nbl;                // bucket-major count array
    const int nbuck = (N + 255) / 256;        // 196 coarse buckets

    // workspace carve-out (~101 MB)
    char* p = (char*)d_ws;
    auto alloc = [&](size_t bytes) -> char* {
        char* q = p;
        p += (bytes + 255) & ~(size_t)255;
        return q;
    };
    int*    offsN = (int*)alloc((size_t)(N + 1) * 4);
    int*    bh    = (int*)alloc((size_t)(nbh + 1) * 4);
    int*    bsums = (int*)alloc(1024 * 4);
    int*    ce    = (int*)alloc((size_t)E * 4);
    int*    ssrc  = (int*)alloc((size_t)E * 4);
    float2* wgtL  = (float2*)alloc((size_t)L * E * 8);
    float*  Z     = (float*)alloc((size_t)N * 192 * 4);
    __half* hf    = (__half*)alloc((size_t)N * D * 2);
    float*  gbuf  = (float*)alloc((size_t)BGRAPH * 2 * L * D * 4);
    ushort* Mhi   = (ushort*)alloc((size_t)L * 4 * 6 * 64 * 8 * 2);
    ushort* Mlo   = (ushort*)alloc((size_t)L * 4 * 6 * 64 * 8 * 2);

    // ---- sort phase: LDS binning only, no global atomics ----
    coarse_hist<<<nbl, 256, 0, stream>>>(dst, bh, E, nbl);
    int nb = (nbh + 255) / 256;               // == nbl (nbh multiple of 256)
    scan1<<<nb, 256, 0, stream>>>(bh, bh, bsums, nbh);   // in-place exclusive ok (elementwise)
    scan2<<<1, 1024, 0, stream>>>(bsums, nb);
    scan3<<<nb, 256, 0, stream>>>(bh, bsums, nbh);
    coarse_scatter<<<nbl, 256, 0, stream>>>(dst, bh, ce, E, nbl);
    fine_sort<<<nbuck, 512, 0, stream>>>(ce, dst, et, src, bh, comp, offsN, ssrc, wgtL,
                                         E, nbl, N);

    buildMfrag<<<(L * 4 * 6 * 64 * 8 + 255) / 256, 256, 0, stream>>>(basis, root, Mhi, Mlo);
    copyX<<<(N * D + 255) / 256, 256, 0, stream>>>(x, Z, hf, N * D);

    // ---- layers ----
    int ggrid = (N + 3) / 4;             // one wave per node
    int tgrid = ((N + 15) / 16 + 3) / 4; // 782
    for (int l = 0; l < L; ++l) {
        gather_k<<<ggrid, 256, 0, stream>>>(offsN, ssrc, wgtL + (size_t)l * E,
                                            (const __half2*)hf, Z, N);
        transform_k<<<tgrid, 256, 0, stream>>>(Z,
                                               Mhi + (size_t)l * 4 * 6 * 64 * 8,
                                               Mlo + (size_t)l * 4 * 6 * 64 * 8,
                                               bias + (size_t)l * D,
                                               hf, gbuf, l, N);
    }
    mlp4<<<BGRAPH / 4, 256, 0, stream>>>(gbuf, w1, b1, w2, b2, out);
}

// Round 8
// 344.969 us; speedup vs baseline: 1.2426x; 1.0318x over previous
//
#include <hip/hip_runtime.h>
#include <hip/hip_fp16.h>
#include <math.h>

// Problem constants (fixed by the reference setup_inputs)
#define D      64
#define L      4
#define R      5
#define BGRAPH 1024
#define CT     4096          // edges per coarse-binning block
#define INVCAP 12288         // LDS rank-inversion capacity (avg bucket ~6.1K)

typedef __attribute__((ext_vector_type(8))) short short8;
typedef __attribute__((ext_vector_type(4))) float f32x4;

__device__ __forceinline__ ushort f2bf(float f) {          // RTN-even fp32->bf16
    unsigned u = __float_as_uint(f);
    return (ushort)((u + 0x7FFFu + ((u >> 16) & 1u)) >> 16);
}
__device__ __forceinline__ float bf2f(ushort h) {
    return __uint_as_float(((unsigned)h) << 16);
}

// ================= two-level MSD sort by dst (no global atomics) =================
// coarse bucket = dst>>8 (196 buckets of 256 nodes); per-block LDS binning.
// pe[pos] = src(16b) | et<<16(3b) | (dst&255)<<19(8b)  -- full payload packed.

__global__ void coarse_hist(const int* __restrict__ dst, int* __restrict__ bh,
                            int E, int nbl) {
    __shared__ int cnt[256];
    cnt[threadIdx.x] = 0;
    __syncthreads();
    int base = blockIdx.x * CT;
    int end = base + CT < E ? base + CT : E;
    for (int i = base + threadIdx.x; i < end; i += 256)
        atomicAdd(&cnt[dst[i] >> 8], 1);
    __syncthreads();
    bh[threadIdx.x * nbl + blockIdx.x] = cnt[threadIdx.x];   // [bucket][block]
}

__global__ void scan1(const int* __restrict__ hist, int* __restrict__ offs,
                      int* __restrict__ bsums, int n) {
    __shared__ int tmp[256];
    int i = blockIdx.x * 256 + threadIdx.x;
    int v = (i < n) ? hist[i] : 0;
    tmp[threadIdx.x] = v;
    __syncthreads();
    for (int o = 1; o < 256; o <<= 1) {
        int t = 0;
        if (threadIdx.x >= o) t = tmp[threadIdx.x - o];
        __syncthreads();
        if (threadIdx.x >= o) tmp[threadIdx.x] += t;
        __syncthreads();
    }
    if (i < n) offs[i] = tmp[threadIdx.x] - v;   // exclusive
    if (threadIdx.x == 255) bsums[blockIdx.x] = tmp[255];
}

__global__ void scan2(int* __restrict__ bsums, int nb) {
    __shared__ int tmp[1024];
    int v = (threadIdx.x < nb) ? bsums[threadIdx.x] : 0;
    tmp[threadIdx.x] = v;
    __syncthreads();
    for (int o = 1; o < 1024; o <<= 1) {
        int t = 0;
        if (threadIdx.x >= o) t = tmp[threadIdx.x - o];
        __syncthreads();
        if (threadIdx.x >= o) tmp[threadIdx.x] += t;
        __syncthreads();
    }
    if (threadIdx.x < nb) bsums[threadIdx.x] = tmp[threadIdx.x] - v;  // exclusive
}

__global__ void scan3(int* __restrict__ offs, const int* __restrict__ bsums, int n) {
    int i = blockIdx.x * 256 + threadIdx.x;
    if (i < n) offs[i] += bsums[blockIdx.x];
}

__global__ void coarse_scatter(const int* __restrict__ dst, const int* __restrict__ src,
                               const int* __restrict__ et, const int* __restrict__ bh,
                               int* __restrict__ pe, int E, int nbl) {
    __shared__ int cur[256];
    cur[threadIdx.x] = bh[threadIdx.x * nbl + blockIdx.x];
    __syncthreads();
    int base = blockIdx.x * CT;
    int end = base + CT < E ? base + CT : E;
    for (int i = base + threadIdx.x; i < end; i += 256) {
        int d = dst[i];
        int pos = atomicAdd(&cur[d >> 8], 1);            // LDS atomic only
        pe[pos] = src[i] | (et[i] << 16) | ((d & 255) << 19);
    }
}

// fine pass: one block per coarse bucket; only touches pe[] (linear reads).
// Ranks edges in LDS, then emits meta[pos]=(src|et<<16, 1/cnt(dst,et)) COALESCED.
__global__ __launch_bounds__(512)
void fine_sort(const int* __restrict__ pe, const int* __restrict__ bh,
               int* __restrict__ offs, int2* __restrict__ meta,
               int E, int nbl, int N) {
    __shared__ int cnt[256];
    __shared__ int pref[256];
    __shared__ int cur[256];
    __shared__ int cntR[256 * R];
    __shared__ int inv[INVCAP];
    int b = blockIdx.x, t = threadIdx.x;
    int rbeg = bh[b * nbl];
    int rend = (b == gridDim.x - 1) ? E : bh[(b + 1) * nbl];
    int sz = rend - rbeg;
    if (t < 256) { cnt[t] = 0; cur[t] = 0; }
    for (int k = t; k < 256 * R; k += 512) cntR[k] = 0;
    __syncthreads();
    // phase 1: counts per node and per (node, rel)
    for (int i = rbeg + t; i < rend; i += 512) {
        int pk = pe[i];
        int ln = (pk >> 19) & 255;
        atomicAdd(&cnt[ln], 1);
        atomicAdd(&cntR[ln * R + ((pk >> 16) & 7)], 1);
    }
    __syncthreads();
    // phase 2: scan 256 node counters; write offs; invert counts
    if (t < 256) pref[t] = cnt[t];
    __syncthreads();
    for (int o = 1; o < 256; o <<= 1) {
        int tv = 0;
        if (t >= o && t < 256) tv = pref[t - o];
        __syncthreads();
        if (t >= o && t < 256) pref[t] += tv;
        __syncthreads();
    }
    if (t < 256) {
        int node = b * 256 + t;
        if (node <= N) offs[node] = rbeg + pref[t] - cnt[t];  // b=195,t=80 -> offs[N]=E
    }
    for (int k = t; k < 256 * R; k += 512) {
        int c = cntR[k];
        ((float*)cntR)[k] = 1.0f / (float)(c > 0 ? c : 1);
    }
    __syncthreads();
    if (sz <= INVCAP) {
        // phase 3a: rank into LDS
        for (int i = rbeg + t; i < rend; i += 512) {
            int pk = pe[i];
            int ln = (pk >> 19) & 255;
            int lp = pref[ln] - cnt[ln] + atomicAdd(&cur[ln], 1);
            inv[lp] = pk;
        }
        __syncthreads();
        // phase 3b: coalesced payload emit
        for (int k = t; k < sz; k += 512) {
            int pk = inv[k];
            int ln = (pk >> 19) & 255, r = (pk >> 16) & 7;
            meta[rbeg + k] = make_int2(pk & 0x7FFFF,
                                       __float_as_int(((float*)cntR)[ln * R + r]));
        }
    } else {
        // fallback (bucket too big for LDS): scattered writes, still correct
        for (int i = rbeg + t; i < rend; i += 512) {
            int pk = pe[i];
            int ln = (pk >> 19) & 255, r = (pk >> 16) & 7;
            int pos = rbeg + (pref[ln] - cnt[ln]) + atomicAdd(&cur[ln], 1);
            meta[pos] = make_int2(pk & 0x7FFFF,
                                  __float_as_int(((float*)cntR)[ln * R + r]));
        }
    }
}

// ---- M in split-bf16 B-fragment layout: [l][cg][kt][lane][8], k-rows = [B0|B1|root] ----
__global__ void buildMfrag(const float* __restrict__ basis, const float* __restrict__ root,
                           ushort* __restrict__ Mhi, ushort* __restrict__ Mlo) {
    int t = blockIdx.x * 256 + threadIdx.x;
    if (t >= L * 4 * 6 * 64 * 8) return;
    int j = t & 7;
    int lane = (t >> 3) & 63;
    int rem = t >> 9;              // ((l*4+cg)*6+kt)
    int kt = rem % 6;
    int lcg = rem / 6;
    int cg = lcg & 3, l = lcg >> 2;
    int k = kt * 32 + (lane >> 4) * 8 + j;
    int col = cg * 16 + (lane & 15);
    float val;
    if (k < 64)       val = basis[(((size_t)l * 2 + 0) * D + k) * D + col];
    else if (k < 128) val = basis[(((size_t)l * 2 + 1) * D + (k - 64)) * D + col];
    else              val = root[((size_t)l * D + (k - 128)) * D + col];
    ushort hi = f2bf(val);
    Mhi[t] = hi;
    Mlo[t] = f2bf(val - bf2f(hi));
}

// ---- x -> Z h-cols (fp32) + hf (fp16 gather copy) ----
__global__ void copyX(const float* __restrict__ x, float* __restrict__ Z,
                      __half* __restrict__ hf, int NE) {
    int i = blockIdx.x * 256 + threadIdx.x;
    if (i >= NE) return;
    float v = x[i];
    Z[(size_t)(i >> 6) * 192 + 128 + (i & 63)] = v;
    hf[i] = __float2half(v);
}

// ---- gather: one wave per node; lane = (edge-in-pair, dim-pair)
// one half2 dword load fetches 2 full rows per wave; comp via broadcast LDS wtab.
__global__ __launch_bounds__(256)
void gather_k(const int* __restrict__ offs, const int2* __restrict__ meta,
              const __half2* __restrict__ hf2, const float* __restrict__ comp_l,
              float* __restrict__ Z, int N) {
    __shared__ float2 wtab[8];
    if (threadIdx.x < R)
        wtab[threadIdx.x] = make_float2(comp_l[2 * threadIdx.x], comp_l[2 * threadIdx.x + 1]);
    __syncthreads();
    int wid = threadIdx.x >> 6, lane = threadIdx.x & 63;
    int v = blockIdx.x * 4 + wid;
    if (v >= N) return;
    int h = lane >> 5, d2 = lane & 31;
    int b = offs[v], e2 = offs[v + 1];
    float s0l = 0.f, s0h = 0.f, s1l = 0.f, s1h = 0.f;
    #pragma unroll 4
    for (int i = b; i < e2; i += 2) {
        int gi = i + h;
        bool live = gi < e2;
        gi = live ? gi : e2 - 1;
        int2 m = meta[gi];                        // 2-way broadcast load
        int s = m.x & 0xFFFF;
        int r = m.x >> 16;                        // et (bits 16..18)
        float ic = live ? __int_as_float(m.y) : 0.f;
        float2 wt = wtab[r];                      // same addr across half-wave: broadcast
        float w0 = wt.x * ic, w1 = wt.y * ic;
        __half2 hv = hf2[(size_t)s * 32 + d2];    // 2 edges x 128B per wave-VMEM
        float lo = __low2float(hv), hi = __high2float(hv);
        s0l = fmaf(w0, lo, s0l); s0h = fmaf(w0, hi, s0h);
        s1l = fmaf(w1, lo, s1l); s1h = fmaf(w1, hi, s1h);
    }
    s0l += __shfl_xor(s0l, 32); s0h += __shfl_xor(s0h, 32);
    s1l += __shfl_xor(s1l, 32); s1h += __shfl_xor(s1h, 32);
    if (h == 0) {
        *(float2*)(Z + (size_t)v * 192 + 2 * d2)      = make_float2(s0l, s0h);
        *(float2*)(Z + (size_t)v * 192 + 64 + 2 * d2) = make_float2(s1l, s1h);
    }
}

// ---- transform: tanh([z0|z1|h] @ M + bias) via split-bf16 MFMA; IN-PLACE on Z ----
// (each wave reads only the 16 rows it later writes -> no cross-thread hazard)
__global__ __launch_bounds__(256)
void transform_k(float* __restrict__ Z, const ushort* __restrict__ Mhi_l,
                 const ushort* __restrict__ Mlo_l, const float* __restrict__ bias_l,
                 __half* __restrict__ hfo, float* __restrict__ g, int l, int N) {
    int wid = threadIdx.x >> 6, lane = threadIdx.x & 63;
    int tile = blockIdx.x * 4 + wid;
    if (tile * 16 >= N) return;
    int m = lane & 15, lg = lane >> 4;

    // A-frags straight from Z: lane holds row (tile*16+m), k = lg*8 .. +7 per k-tile
    const float* arow = Z + (size_t)(tile * 16 + m) * 192 + lg * 8;
    short8 ahi[6], alo[6];
    #pragma unroll
    for (int kt = 0; kt < 6; ++kt) {
        f32x4 x0 = *(const f32x4*)(arow + kt * 32);
        f32x4 x1 = *(const f32x4*)(arow + kt * 32 + 4);
        union { short8 v; ushort u[8]; } H, Lw;
        #pragma unroll
        for (int q = 0; q < 8; ++q) {
            float f = q < 4 ? x0[q] : x1[q - 4];
            ushort hi = f2bf(f);
            H.u[q] = hi;
            Lw.u[q] = f2bf(f - bf2f(hi));
        }
        ahi[kt] = H.v;
        alo[kt] = Lw.v;
    }

    #pragma unroll
    for (int cg = 0; cg < 4; ++cg) {
        int col = cg * 16 + m;
        float bv = bias_l[col];
        f32x4 acc = { bv, bv, bv, bv };
        #pragma unroll
        for (int kt = 0; kt < 6; ++kt) {
            size_t boff = ((size_t)(cg * 6 + kt) * 64 + lane) * 8;
            short8 bhi = *(const short8*)(Mhi_l + boff);
            short8 blo = *(const short8*)(Mlo_l + boff);
            acc = __builtin_amdgcn_mfma_f32_16x16x32_bf16(ahi[kt], bhi, acc, 0, 0, 0);
            acc = __builtin_amdgcn_mfma_f32_16x16x32_bf16(ahi[kt], blo, acc, 0, 0, 0);
            acc = __builtin_amdgcn_mfma_f32_16x16x32_bf16(alo[kt], bhi, acc, 0, 0, 0);
        }
        int rowbase = tile * 16 + lg * 4;      // C/D: col=lane&15, row=(lane>>4)*4+reg
        #pragma unroll
        for (int r = 0; r < 4; ++r) {
            int node = rowbase + r;
            float tv = tanhf(acc[r]);
            Z[(size_t)node * 192 + 128 + col] = tv;
            hfo[node * D + col] = __float2half(tv);
            if (node < BGRAPH)
                g[(size_t)node * (2 * L * D) + l * D + col] = tv;
            else if (node < 2 * BGRAPH)
                g[(size_t)(node - BGRAPH) * (2 * L * D) + L * D + l * D + col] = tv;
        }
    }
}

// ---- final MLP: 4 rows per block; w1 streamed once per block ----
__global__ void mlp4(const float* __restrict__ g, const float* __restrict__ w1,
                     const float* __restrict__ b1, const float* __restrict__ w2,
                     const float* __restrict__ b2, float* __restrict__ out) {
    __shared__ float gl[4][512];
    __shared__ float red[2][4][128];
    int tid = threadIdx.x;
    int rowbase = blockIdx.x * 4;
    for (int i = tid; i < 4 * 512; i += 256)
        gl[i >> 9][i & 511] = g[(size_t)rowbase * 512 + i];
    __syncthreads();
    int t = tid & 127, kh = tid >> 7;
    float s0 = 0.f, s1 = 0.f, s2 = 0.f, s3 = 0.f;
    int k0 = kh * 256;
    #pragma unroll 4
    for (int k = k0; k < k0 + 256; ++k) {
        float wv = w1[k * 128 + t];
        s0 = fmaf(gl[0][k], wv, s0);
        s1 = fmaf(gl[1][k], wv, s1);
        s2 = fmaf(gl[2][k], wv, s2);
        s3 = fmaf(gl[3][k], wv, s3);
    }
    red[kh][0][t] = s0; red[kh][1][t] = s1; red[kh][2][t] = s2; red[kh][3][t] = s3;
    __syncthreads();
    if (kh == 0) {
        #pragma unroll
        for (int r = 0; r < 4; ++r)
            gl[r][t] = fmaxf(red[0][r][t] + red[1][r][t] + b1[t], 0.f) * w2[t];
    }
    __syncthreads();
    int w = tid >> 6, lane = tid & 63;
    float val = gl[w][lane] + gl[w][lane + 64];
    #pragma unroll
    for (int o = 32; o > 0; o >>= 1) val += __shfl_down(val, o);
    if (lane == 0) out[rowbase + w] = val + b2[0];
}

extern "C" void kernel_launch(void* const* d_in, const int* in_sizes, int n_in,
                              void* d_out, int out_size, void* d_ws, size_t ws_size,
                              hipStream_t stream) {
    const float* x     = (const float*)d_in[0];
    const float* basis = (const float*)d_in[1];
    const float* comp  = (const float*)d_in[2];
    const float* root  = (const float*)d_in[3];
    const float* bias  = (const float*)d_in[4];
    const float* w1    = (const float*)d_in[5];
    const float* b1    = (const float*)d_in[6];
    const float* w2    = (const float*)d_in[7];
    const float* b2    = (const float*)d_in[8];
    const int*   src   = (const int*)d_in[9];
    const int*   dst   = (const int*)d_in[10];
    const int*   et    = (const int*)d_in[11];
    float* out = (float*)d_out;

    const int N = in_sizes[0] / D;   // 50000
    const int E = in_sizes[9];       // 1200000

    const int nbl = (E + CT - 1) / CT;        // 293 coarse blocks
    const int nbh = 256 * nbl;                // bucket-major count array
    const int nbuck = (N + 255) / 256;        // 196 coarse buckets

    // workspace carve-out (~62 MB)
    char* p = (char*)d_ws;
    auto alloc = [&](size_t bytes) -> char* {
        char* q = p;
        p += (bytes + 255) & ~(size_t)255;
        return q;
    };
    int*    offsN = (int*)alloc((size_t)(N + 1) * 4);
    int*    bh    = (int*)alloc((size_t)(nbh + 1) * 4);
    int*    bsums = (int*)alloc(1024 * 4);
    int*    pe    = (int*)alloc((size_t)E * 4);
    int2*   meta  = (int2*)alloc((size_t)E * 8);
    float*  Z     = (float*)alloc((size_t)N * 192 * 4);
    __half* hf    = (__half*)alloc((size_t)N * D * 2);
    float*  gbuf  = (float*)alloc((size_t)BGRAPH * 2 * L * D * 4);
    ushort* Mhi   = (ushort*)alloc((size_t)L * 4 * 6 * 64 * 8 * 2);
    ushort* Mlo   = (ushort*)alloc((size_t)L * 4 * 6 * 64 * 8 * 2);

    // ---- sort phase: LDS binning only, no global atomics ----
    coarse_hist<<<nbl, 256, 0, stream>>>(dst, bh, E, nbl);
    int nb = (nbh + 255) / 256;               // == nbl (nbh multiple of 256)
    scan1<<<nb, 256, 0, stream>>>(bh, bh, bsums, nbh);   // in-place exclusive ok (elementwise)
    scan2<<<1, 1024, 0, stream>>>(bsums, nb);
    scan3<<<nb, 256, 0, stream>>>(bh, bsums, nbh);
    coarse_scatter<<<nbl, 256, 0, stream>>>(dst, src, et, bh, pe, E, nbl);
    fine_sort<<<nbuck, 512, 0, stream>>>(pe, bh, offsN, meta, E, nbl, N);

    buildMfrag<<<(L * 4 * 6 * 64 * 8 + 255) / 256, 256, 0, stream>>>(basis, root, Mhi, Mlo);
    copyX<<<(N * D + 255) / 256, 256, 0, stream>>>(x, Z, hf, N * D);

    // ---- layers ----
    int ggrid = (N + 3) / 4;             // one wave per node
    int tgrid = ((N + 15) / 16 + 3) / 4; // 782
    for (int l = 0; l < L; ++l) {
        gather_k<<<ggrid, 256, 0, stream>>>(offsN, meta, (const __half2*)hf,
                                            comp + (size_t)l * R * 2, Z, N);
        transform_k<<<tgrid, 256, 0, stream>>>(Z,
                                               Mhi + (size_t)l * 4 * 6 * 64 * 8,
                                               Mlo + (size_t)l * 4 * 6 * 64 * 8,
                                               bias + (size_t)l * D,
                                               hf, gbuf, l, N);
    }
    mlp4<<<BGRAPH / 4, 256, 0, stream>>>(gbuf, w1, b1, w2, b2, out);
}

// Round 9
// 287.535 us; speedup vs baseline: 1.4908x; 1.1997x over previous
//
#include <hip/hip_runtime.h>
#include <hip/hip_fp16.h>
#include <math.h>

// Problem constants (fixed by the reference setup_inputs)
#define D      64
#define L      4
#define R      5
#define BGRAPH 1024
#define CT     4096          // edges per coarse-binning block
#define INVCAP 12288         // LDS rank-inversion capacity (avg bucket ~6.1K)

typedef __attribute__((ext_vector_type(8))) short short8;
typedef __attribute__((ext_vector_type(4))) float f32x4;

__device__ __forceinline__ ushort f2bf(float f) {          // RTN-even fp32->bf16
    unsigned u = __float_as_uint(f);
    return (ushort)((u + 0x7FFFu + ((u >> 16) & 1u)) >> 16);
}
__device__ __forceinline__ float bf2f(ushort h) {
    return __uint_as_float(((unsigned)h) << 16);
}

// ================= two-level MSD sort by dst (no global atomics) =================
// coarse bucket = dst>>8 (196 buckets of 256 nodes); per-block LDS binning.
// pe[pos] = src(16b) | et<<16(3b) | (dst&255)<<19(8b)  -- full payload packed.

__global__ void coarse_hist(const int* __restrict__ dst, int* __restrict__ bh,
                            int E, int nbl) {
    __shared__ int cnt[256];
    cnt[threadIdx.x] = 0;
    __syncthreads();
    int base = blockIdx.x * CT;
    int end = base + CT < E ? base + CT : E;
    for (int i = base + threadIdx.x; i < end; i += 256)
        atomicAdd(&cnt[dst[i] >> 8], 1);
    __syncthreads();
    bh[threadIdx.x * nbl + blockIdx.x] = cnt[threadIdx.x];   // [bucket][block]
}

__global__ void scan1(const int* __restrict__ hist, int* __restrict__ offs,
                      int* __restrict__ bsums, int n) {
    __shared__ int tmp[256];
    int i = blockIdx.x * 256 + threadIdx.x;
    int v = (i < n) ? hist[i] : 0;
    tmp[threadIdx.x] = v;
    __syncthreads();
    for (int o = 1; o < 256; o <<= 1) {
        int t = 0;
        if (threadIdx.x >= o) t = tmp[threadIdx.x - o];
        __syncthreads();
        if (threadIdx.x >= o) tmp[threadIdx.x] += t;
        __syncthreads();
    }
    if (i < n) offs[i] = tmp[threadIdx.x] - v;   // exclusive
    if (threadIdx.x == 255) bsums[blockIdx.x] = tmp[255];
}

__global__ void scan2(int* __restrict__ bsums, int nb) {
    __shared__ int tmp[1024];
    int v = (threadIdx.x < nb) ? bsums[threadIdx.x] : 0;
    tmp[threadIdx.x] = v;
    __syncthreads();
    for (int o = 1; o < 1024; o <<= 1) {
        int t = 0;
        if (threadIdx.x >= o) t = tmp[threadIdx.x - o];
        __syncthreads();
        if (threadIdx.x >= o) tmp[threadIdx.x] += t;
        __syncthreads();
    }
    if (threadIdx.x < nb) bsums[threadIdx.x] = tmp[threadIdx.x] - v;  // exclusive
}

__global__ void scan3(int* __restrict__ offs, const int* __restrict__ bsums, int n) {
    int i = blockIdx.x * 256 + threadIdx.x;
    if (i < n) offs[i] += bsums[blockIdx.x];
}

__global__ void coarse_scatter(const int* __restrict__ dst, const int* __restrict__ src,
                               const int* __restrict__ et, const int* __restrict__ bh,
                               int* __restrict__ pe, int E, int nbl) {
    __shared__ int cur[256];
    cur[threadIdx.x] = bh[threadIdx.x * nbl + blockIdx.x];
    __syncthreads();
    int base = blockIdx.x * CT;
    int end = base + CT < E ? base + CT : E;
    for (int i = base + threadIdx.x; i < end; i += 256) {
        int d = dst[i];
        int pos = atomicAdd(&cur[d >> 8], 1);            // LDS atomic only
        pe[pos] = src[i] | (et[i] << 16) | ((d & 255) << 19);
    }
}

// fine pass: one block per coarse bucket; only touches pe[] (linear reads).
// Ranks edges in LDS, then emits meta[pos]=(src|et<<16, 1/cnt(dst,et)) COALESCED.
__global__ __launch_bounds__(512)
void fine_sort(const int* __restrict__ pe, const int* __restrict__ bh,
               int* __restrict__ offs, int2* __restrict__ meta,
               int E, int nbl, int N) {
    __shared__ int cnt[256];
    __shared__ int pref[256];
    __shared__ int cur[256];
    __shared__ int cntR[256 * R];
    __shared__ int inv[INVCAP];
    int b = blockIdx.x, t = threadIdx.x;
    int rbeg = bh[b * nbl];
    int rend = (b == gridDim.x - 1) ? E : bh[(b + 1) * nbl];
    int sz = rend - rbeg;
    if (t < 256) { cnt[t] = 0; cur[t] = 0; }
    for (int k = t; k < 256 * R; k += 512) cntR[k] = 0;
    __syncthreads();
    // phase 1: counts per node and per (node, rel)
    for (int i = rbeg + t; i < rend; i += 512) {
        int pk = pe[i];
        int ln = (pk >> 19) & 255;
        atomicAdd(&cnt[ln], 1);
        atomicAdd(&cntR[ln * R + ((pk >> 16) & 7)], 1);
    }
    __syncthreads();
    // phase 2: scan 256 node counters; write offs; invert counts
    if (t < 256) pref[t] = cnt[t];
    __syncthreads();
    for (int o = 1; o < 256; o <<= 1) {
        int tv = 0;
        if (t >= o && t < 256) tv = pref[t - o];
        __syncthreads();
        if (t >= o && t < 256) pref[t] += tv;
        __syncthreads();
    }
    if (t < 256) {
        int node = b * 256 + t;
        if (node <= N) offs[node] = rbeg + pref[t] - cnt[t];  // b=195,t=80 -> offs[N]=E
    }
    for (int k = t; k < 256 * R; k += 512) {
        int c = cntR[k];
        ((float*)cntR)[k] = 1.0f / (float)(c > 0 ? c : 1);
    }
    __syncthreads();
    if (sz <= INVCAP) {
        // phase 3a: rank into LDS
        for (int i = rbeg + t; i < rend; i += 512) {
            int pk = pe[i];
            int ln = (pk >> 19) & 255;
            int lp = pref[ln] - cnt[ln] + atomicAdd(&cur[ln], 1);
            inv[lp] = pk;
        }
        __syncthreads();
        // phase 3b: coalesced payload emit
        for (int k = t; k < sz; k += 512) {
            int pk = inv[k];
            int ln = (pk >> 19) & 255, r = (pk >> 16) & 7;
            meta[rbeg + k] = make_int2(pk & 0x7FFFF,
                                       __float_as_int(((float*)cntR)[ln * R + r]));
        }
    } else {
        // fallback (bucket too big for LDS): scattered writes, still correct
        for (int i = rbeg + t; i < rend; i += 512) {
            int pk = pe[i];
            int ln = (pk >> 19) & 255, r = (pk >> 16) & 7;
            int pos = rbeg + (pref[ln] - cnt[ln]) + atomicAdd(&cur[ln], 1);
            meta[pos] = make_int2(pk & 0x7FFFF,
                                  __float_as_int(((float*)cntR)[ln * R + r]));
        }
    }
}

// ---- M in split-bf16 B-fragment layout: [l][cg][kt][lane][8], k-rows = [B0|B1|root] ----
__global__ void buildMfrag(const float* __restrict__ basis, const float* __restrict__ root,
                           ushort* __restrict__ Mhi, ushort* __restrict__ Mlo) {
    int t = blockIdx.x * 256 + threadIdx.x;
    if (t >= L * 4 * 6 * 64 * 8) return;
    int j = t & 7;
    int lane = (t >> 3) & 63;
    int rem = t >> 9;              // ((l*4+cg)*6+kt)
    int kt = rem % 6;
    int lcg = rem / 6;
    int cg = lcg & 3, l = lcg >> 2;
    int k = kt * 32 + (lane >> 4) * 8 + j;
    int col = cg * 16 + (lane & 15);
    float val;
    if (k < 64)       val = basis[(((size_t)l * 2 + 0) * D + k) * D + col];
    else if (k < 128) val = basis[(((size_t)l * 2 + 1) * D + (k - 64)) * D + col];
    else              val = root[((size_t)l * D + (k - 128)) * D + col];
    ushort hi = f2bf(val);
    Mhi[t] = hi;
    Mlo[t] = f2bf(val - bf2f(hi));
}

// ---- x -> Z h-cols (fp32) + hf (fp16 gather copy) ----
__global__ void copyX(const float* __restrict__ x, float* __restrict__ Z,
                      __half* __restrict__ hf, int NE) {
    int i = blockIdx.x * 256 + threadIdx.x;
    if (i >= NE) return;
    float v = x[i];
    Z[(size_t)(i >> 6) * 192 + 128 + (i & 63)] = v;
    hf[i] = __float2half(v);
}

// ---- gather: one wave per node; lane = (edge h=lane>>4, dim-quad q=lane&15)
// one 8B/lane load fetches FOUR full 128B rows per wave-VMEM (4 edges/iter).
__global__ __launch_bounds__(256)
void gather_k(const int* __restrict__ offs, const int2* __restrict__ meta,
              const float2* __restrict__ hf4, const float* __restrict__ comp_l,
              float* __restrict__ Z, int N) {
    __shared__ float2 wtab[8];
    if (threadIdx.x < R)
        wtab[threadIdx.x] = make_float2(comp_l[2 * threadIdx.x], comp_l[2 * threadIdx.x + 1]);
    __syncthreads();
    int wid = threadIdx.x >> 6, lane = threadIdx.x & 63;
    int v = blockIdx.x * 4 + wid;
    if (v >= N) return;
    int h = lane >> 4, q = lane & 15;
    int b = offs[v], e2 = offs[v + 1];
    float s0[4] = {0.f, 0.f, 0.f, 0.f}, s1[4] = {0.f, 0.f, 0.f, 0.f};
    #pragma unroll 4
    for (int i = b; i < e2; i += 4) {
        int gi = i + h;
        bool live = gi < e2;
        gi = live ? gi : e2 - 1;
        int2 m = meta[gi];                        // 4-way broadcast (quarter-wave)
        int s = m.x & 0xFFFF;
        int r = (m.x >> 16) & 7;
        float ic = live ? __int_as_float(m.y) : 0.f;
        float2 wt = wtab[r];
        float w0 = wt.x * ic, w1 = wt.y * ic;
        float2 hv = hf4[(size_t)s * 16 + q];      // 4 edges x 128B per wave-VMEM
        __half2 ha = *(__half2*)&hv.x;
        __half2 hb = *(__half2*)&hv.y;
        float f0 = __low2float(ha), f1 = __high2float(ha);
        float f2 = __low2float(hb), f3 = __high2float(hb);
        s0[0] = fmaf(w0, f0, s0[0]); s0[1] = fmaf(w0, f1, s0[1]);
        s0[2] = fmaf(w0, f2, s0[2]); s0[3] = fmaf(w0, f3, s0[3]);
        s1[0] = fmaf(w1, f0, s1[0]); s1[1] = fmaf(w1, f1, s1[1]);
        s1[2] = fmaf(w1, f2, s1[2]); s1[3] = fmaf(w1, f3, s1[3]);
    }
    #pragma unroll
    for (int k = 0; k < 4; ++k) {
        s0[k] += __shfl_xor(s0[k], 16); s0[k] += __shfl_xor(s0[k], 32);
        s1[k] += __shfl_xor(s1[k], 16); s1[k] += __shfl_xor(s1[k], 32);
    }
    if (h == 0) {
        f32x4 o0 = { s0[0], s0[1], s0[2], s0[3] };
        f32x4 o1 = { s1[0], s1[1], s1[2], s1[3] };
        *(f32x4*)(Z + (size_t)v * 192 + 4 * q)      = o0;
        *(f32x4*)(Z + (size_t)v * 192 + 64 + 4 * q) = o1;
    }
}

// ---- transform: tanh([z0|z1|h] @ M + bias) via split-bf16 MFMA; IN-PLACE on Z ----
// (each wave reads only the 16 rows it later writes -> no cross-thread hazard)
__global__ __launch_bounds__(256)
void transform_k(float* __restrict__ Z, const ushort* __restrict__ Mhi_l,
                 const ushort* __restrict__ Mlo_l, const float* __restrict__ bias_l,
                 __half* __restrict__ hfo, float* __restrict__ g, int l, int N) {
    int wid = threadIdx.x >> 6, lane = threadIdx.x & 63;
    int tile = blockIdx.x * 4 + wid;
    if (tile * 16 >= N) return;
    int m = lane & 15, lg = lane >> 4;

    // A-frags straight from Z: lane holds row (tile*16+m), k = lg*8 .. +7 per k-tile
    const float* arow = Z + (size_t)(tile * 16 + m) * 192 + lg * 8;
    short8 ahi[6], alo[6];
    #pragma unroll
    for (int kt = 0; kt < 6; ++kt) {
        f32x4 x0 = *(const f32x4*)(arow + kt * 32);
        f32x4 x1 = *(const f32x4*)(arow + kt * 32 + 4);
        union { short8 v; ushort u[8]; } H, Lw;
        #pragma unroll
        for (int q = 0; q < 8; ++q) {
            float f = q < 4 ? x0[q] : x1[q - 4];
            ushort hi = f2bf(f);
            H.u[q] = hi;
            Lw.u[q] = f2bf(f - bf2f(hi));
        }
        ahi[kt] = H.v;
        alo[kt] = Lw.v;
    }

    #pragma unroll
    for (int cg = 0; cg < 4; ++cg) {
        int col = cg * 16 + m;
        float bv = bias_l[col];
        f32x4 acc = { bv, bv, bv, bv };
        #pragma unroll
        for (int kt = 0; kt < 6; ++kt) {
            size_t boff = ((size_t)(cg * 6 + kt) * 64 + lane) * 8;
            short8 bhi = *(const short8*)(Mhi_l + boff);
            short8 blo = *(const short8*)(Mlo_l + boff);
            acc = __builtin_amdgcn_mfma_f32_16x16x32_bf16(ahi[kt], bhi, acc, 0, 0, 0);
            acc = __builtin_amdgcn_mfma_f32_16x16x32_bf16(ahi[kt], blo, acc, 0, 0, 0);
            acc = __builtin_amdgcn_mfma_f32_16x16x32_bf16(alo[kt], bhi, acc, 0, 0, 0);
        }
        int rowbase = tile * 16 + lg * 4;      // C/D: col=lane&15, row=(lane>>4)*4+reg
        #pragma unroll
        for (int r = 0; r < 4; ++r) {
            int node = rowbase + r;
            float tv = tanhf(acc[r]);
            Z[(size_t)node * 192 + 128 + col] = tv;
            hfo[node * D + col] = __float2half(tv);
            if (node < BGRAPH)
                g[(size_t)node * (2 * L * D) + l * D + col] = tv;
            else if (node < 2 * BGRAPH)
                g[(size_t)(node - BGRAPH) * (2 * L * D) + L * D + l * D + col] = tv;
        }
    }
}

// ---- final MLP: 4 rows per block; w1 streamed once per block ----
__global__ void mlp4(const float* __restrict__ g, const float* __restrict__ w1,
                     const float* __restrict__ b1, const float* __restrict__ w2,
                     const float* __restrict__ b2, float* __restrict__ out) {
    __shared__ float gl[4][512];
    __shared__ float red[2][4][128];
    int tid = threadIdx.x;
    int rowbase = blockIdx.x * 4;
    for (int i = tid; i < 4 * 512; i += 256)
        gl[i >> 9][i & 511] = g[(size_t)rowbase * 512 + i];
    __syncthreads();
    int t = tid & 127, kh = tid >> 7;
    float s0 = 0.f, s1 = 0.f, s2 = 0.f, s3 = 0.f;
    int k0 = kh * 256;
    #pragma unroll 4
    for (int k = k0; k < k0 + 256; ++k) {
        float wv = w1[k * 128 + t];
        s0 = fmaf(gl[0][k], wv, s0);
        s1 = fmaf(gl[1][k], wv, s1);
        s2 = fmaf(gl[2][k], wv, s2);
        s3 = fmaf(gl[3][k], wv, s3);
    }
    red[kh][0][t] = s0; red[kh][1][t] = s1; red[kh][2][t] = s2; red[kh][3][t] = s3;
    __syncthreads();
    if (kh == 0) {
        #pragma unroll
        for (int r = 0; r < 4; ++r)
            gl[r][t] = fmaxf(red[0][r][t] + red[1][r][t] + b1[t], 0.f) * w2[t];
    }
    __syncthreads();
    int w = tid >> 6, lane = tid & 63;
    float val = gl[w][lane] + gl[w][lane + 64];
    #pragma unroll
    for (int o = 32; o > 0; o >>= 1) val += __shfl_down(val, o);
    if (lane == 0) out[rowbase + w] = val + b2[0];
}

extern "C" void kernel_launch(void* const* d_in, const int* in_sizes, int n_in,
                              void* d_out, int out_size, void* d_ws, size_t ws_size,
                              hipStream_t stream) {
    const float* x     = (const float*)d_in[0];
    const float* basis = (const float*)d_in[1];
    const float* comp  = (const float*)d_in[2];
    const float* root  = (const float*)d_in[3];
    const float* bias  = (const float*)d_in[4];
    const float* w1    = (const float*)d_in[5];
    const float* b1    = (const float*)d_in[6];
    const float* w2    = (const float*)d_in[7];
    const float* b2    = (const float*)d_in[8];
    const int*   src   = (const int*)d_in[9];
    const int*   dst   = (const int*)d_in[10];
    const int*   et    = (const int*)d_in[11];
    float* out = (float*)d_out;

    const int N = in_sizes[0] / D;   // 50000
    const int E = in_sizes[9];       // 1200000

    const int nbl = (E + CT - 1) / CT;        // 293 coarse blocks
    const int nbh = 256 * nbl;                // bucket-major count array
    const int nbuck = (N + 255) / 256;        // 196 coarse buckets

    // workspace carve-out (~62 MB)
    char* p = (char*)d_ws;
    auto alloc = [&](size_t bytes) -> char* {
        char* q = p;
        p += (bytes + 255) & ~(size_t)255;
        return q;
    };
    int*    offsN = (int*)alloc((size_t)(N + 1) * 4);
    int*    bh    = (int*)alloc((size_t)(nbh + 1) * 4);
    int*    bsums = (int*)alloc(1024 * 4);
    int*    pe    = (int*)alloc((size_t)E * 4);
    int2*   meta  = (int2*)alloc((size_t)E * 8);
    float*  Z     = (float*)alloc((size_t)N * 192 * 4);
    __half* hf    = (__half*)alloc((size_t)N * D * 2);
    float*  gbuf  = (float*)alloc((size_t)BGRAPH * 2 * L * D * 4);
    ushort* Mhi   = (ushort*)alloc((size_t)L * 4 * 6 * 64 * 8 * 2);
    ushort* Mlo   = (ushort*)alloc((size_t)L * 4 * 6 * 64 * 8 * 2);

    // ---- sort phase: LDS binning only, no global atomics ----
    coarse_hist<<<nbl, 256, 0, stream>>>(dst, bh, E, nbl);
    int nb = (nbh + 255) / 256;               // == nbl (nbh multiple of 256)
    scan1<<<nb, 256, 0, stream>>>(bh, bh, bsums, nbh);   // in-place exclusive ok (elementwise)
    scan2<<<1, 1024, 0, stream>>>(bsums, nb);
    scan3<<<nb, 256, 0, stream>>>(bh, bsums, nbh);
    coarse_scatter<<<nbl, 256, 0, stream>>>(dst, src, et, bh, pe, E, nbl);
    fine_sort<<<nbuck, 512, 0, stream>>>(pe, bh, offsN, meta, E, nbl, N);

    buildMfrag<<<(L * 4 * 6 * 64 * 8 + 255) / 256, 256, 0, stream>>>(basis, root, Mhi, Mlo);
    copyX<<<(N * D + 255) / 256, 256, 0, stream>>>(x, Z, hf, N * D);

    // ---- layers ----
    int ggrid = (N + 3) / 4;             // one wave per node
    int tgrid = ((N + 15) / 16 + 3) / 4; // 782
    for (int l = 0; l < L; ++l) {
        gather_k<<<ggrid, 256, 0, stream>>>(offsN, meta, (const float2*)hf,
                                            comp + (size_t)l * R * 2, Z, N);
        transform_k<<<tgrid, 256, 0, stream>>>(Z,
                                               Mhi + (size_t)l * 4 * 6 * 64 * 8,
                                               Mlo + (size_t)l * 4 * 6 * 64 * 8,
                                               bias + (size_t)l * D,
                                               hf, gbuf, l, N);
    }
    mlp4<<<BGRAPH / 4, 256, 0, stream>>>(gbuf, w1, b1, w2, b2, out);
}